// Round 5
// baseline (224.631 us; speedup 1.0000x reference)
//
#include <hip/hip_runtime.h>
#include <hip/hip_bf16.h>
#include <cstdint>

#define D_MODEL 1024
#define NHEADS  16
#define DK      64
#define BATCH   4
#define SEQ     2048
#define MROWS   (BATCH * SEQ)   // 8192
#define NQT     (SEQ / 64)      // 32 q-tiles

typedef __attribute__((ext_vector_type(4))) float  f32x4;
typedef __attribute__((ext_vector_type(8))) __bf16 bf16x8;
typedef __attribute__((ext_vector_type(8))) short  short8;

__device__ __forceinline__ unsigned short f2bf(float f) {
    unsigned int u = __float_as_uint(f);
    unsigned int r = (u + 0x7fffu + ((u >> 16) & 1u)) >> 16;
    return (unsigned short)r;
}

__device__ __forceinline__ unsigned int cvtpk_bf16(float lo, float hi) {
    unsigned int r;
    asm volatile("v_cvt_pk_bf16_f32 %0, %1, %2" : "=v"(r) : "v"(lo), "v"(hi));
    return r;
}

// ---------------- fp32 -> bf16 conversion ----------------
__global__ void cvt_bf16(const float* __restrict__ in, unsigned short* __restrict__ out, int n) {
    int i = (blockIdx.x * 256 + threadIdx.x) * 4;
    if (i >= n) return;
    float4 v = *reinterpret_cast<const float4*>(in + i);
    ushort4 o;
    o.x = f2bf(v.x); o.y = f2bf(v.y); o.z = f2bf(v.z); o.w = f2bf(v.w);
    *reinterpret_cast<ushort4*>(out + i) = o;
}

__global__ void cvt_bf16_w(const float* __restrict__ w0, const float* __restrict__ w1,
                           const float* __restrict__ w2, const float* __restrict__ w3,
                           unsigned short* __restrict__ o0, unsigned short* __restrict__ o1,
                           unsigned short* __restrict__ o2, unsigned short* __restrict__ o3,
                           int n) {
    const int z = blockIdx.y;
    const float* in = (z == 0) ? w0 : (z == 1) ? w1 : (z == 2) ? w2 : w3;
    unsigned short* out = (z == 0) ? o0 : (z == 1) ? o1 : (z == 2) ? o2 : o3;
    int i = (blockIdx.x * 256 + threadIdx.x) * 4;
    if (i >= n) return;
    float4 v = *reinterpret_cast<const float4*>(in + i);
    ushort4 o;
    o.x = f2bf(v.x); o.y = f2bf(v.y); o.z = f2bf(v.z); o.w = f2bf(v.w);
    *reinterpret_cast<ushort4*>(out + i) = o;
}

// ---------------- async global->LDS (16B per lane) ----------------
__device__ __forceinline__ void gload_lds16(const void* g, void* l) {
    __builtin_amdgcn_global_load_lds(
        (const __attribute__((address_space(1))) void*)(uintptr_t)g,
        (__attribute__((address_space(3))) void*)(unsigned int)(uintptr_t)l,
        16, 0, 0);
}

// ---------------- bf16 MFMA GEMM, 2-phase double-buffered pipeline ----------------
// C[M][N] = A[M][K] * Bt[N][K]^T
#define BM 128
#define BN 128
#define BK 32

__global__ __launch_bounds__(256) void gemm_bt(
    const unsigned short* __restrict__ A,
    const unsigned short* __restrict__ B0,
    const unsigned short* __restrict__ B1,
    const unsigned short* __restrict__ B2,
    void* __restrict__ C0, void* __restrict__ C1, void* __restrict__ C2,
    int M, int N, int K, int out_f32)
{
    __shared__ __align__(16) unsigned short As[2][BM * BK];
    __shared__ __align__(16) unsigned short Bs[2][BN * BK];

    const int z = blockIdx.z;
    const unsigned short* Bt = (z == 0) ? B0 : ((z == 1) ? B1 : B2);
    void* C = (z == 0) ? C0 : ((z == 1) ? C1 : C2);

    const int tid  = threadIdx.x;
    const int wave = tid >> 6;
    const int lane = tid & 63;
    const int wr   = wave >> 1;   // 0..1
    const int wc   = wave & 1;    // 0..1
    const int bm   = blockIdx.x * BM;
    const int bn   = blockIdx.y * BN;

    f32x4 acc[4][4];
    #pragma unroll
    for (int i = 0; i < 4; i++)
        #pragma unroll
        for (int j = 0; j < 4; j++)
            #pragma unroll
            for (int r = 0; r < 4; r++) acc[i][j][r] = 0.f;

    const int srow = tid >> 2;          // 0..63
    const int scol = (tid & 3) * 8;     // 0,8,16,24

    const int kg = (lane >> 4) * 8;
    const int rl = lane & 15;

    const unsigned short* Arow0 = A  + (size_t)(bm + srow) * K + scol;
    const unsigned short* Arow1 = A  + (size_t)(bm + 64 + srow) * K + scol;
    const unsigned short* Brow0 = Bt + (size_t)(bn + srow) * K + scol;
    const unsigned short* Brow1 = Bt + (size_t)(bn + 64 + srow) * K + scol;

    auto STAGE = [&](int buf, int k0) {
        gload_lds16(Arow0 + k0, &As[buf][0] + wave * 512);
        gload_lds16(Arow1 + k0, &As[buf][0] + 2048 + wave * 512);
        gload_lds16(Brow0 + k0, &Bs[buf][0] + wave * 512);
        gload_lds16(Brow1 + k0, &Bs[buf][0] + 2048 + wave * 512);
    };

    auto COMPUTE = [&](int buf) {
        bf16x8 a[4], b[4];
        #pragma unroll
        for (int mi = 0; mi < 4; mi++) {
            short8 t = *reinterpret_cast<const short8*>(&As[buf][(wr * 64 + mi * 16 + rl) * BK + kg]);
            a[mi] = __builtin_bit_cast(bf16x8, t);
        }
        #pragma unroll
        for (int ni = 0; ni < 4; ni++) {
            short8 t = *reinterpret_cast<const short8*>(&Bs[buf][(wc * 64 + ni * 16 + rl) * BK + kg]);
            b[ni] = __builtin_bit_cast(bf16x8, t);
        }
        #pragma unroll
        for (int mi = 0; mi < 4; mi++)
            #pragma unroll
            for (int ni = 0; ni < 4; ni++)
                acc[mi][ni] = __builtin_amdgcn_mfma_f32_16x16x32_bf16(a[mi], b[ni], acc[mi][ni], 0, 0, 0);
    };

    const int NT = K / BK;

    STAGE(0, 0);
    __syncthreads();

    int cur = 0;
    for (int t = 0; t < NT - 1; ++t) {
        STAGE(cur ^ 1, (t + 1) * BK);
        COMPUTE(cur);
        __syncthreads();
        cur ^= 1;
    }
    COMPUTE(cur);

    const int rg = (lane >> 4) * 4;
    if (out_f32) {
        #pragma unroll
        for (int mi = 0; mi < 4; mi++)
            #pragma unroll
            for (int ni = 0; ni < 4; ni++)
                #pragma unroll
                for (int r = 0; r < 4; r++) {
                    int row = bm + wr * 64 + mi * 16 + rg + r;
                    int col = bn + wc * 64 + ni * 16 + rl;
                    ((float*)C)[(size_t)row * N + col] = acc[mi][ni][r];
                }
    } else {
        #pragma unroll
        for (int mi = 0; mi < 4; mi++)
            #pragma unroll
            for (int ni = 0; ni < 4; ni++)
                #pragma unroll
                for (int r = 0; r < 4; r++) {
                    int row = bm + wr * 64 + mi * 16 + rg + r;
                    int col = bn + wc * 64 + ni * 16 + rl;
                    ((unsigned short*)C)[(size_t)row * N + col] = f2bf(acc[mi][ni][r]);
                }
    }
}

// ---------------- MFMA causal flash attention ----------------
// grid: (B*H, NQT/2). Block p handles q-tiles {p, NQT-1-p}: 33 KV-tiles each.
__global__ __launch_bounds__(256) void attn_mfma(
    const unsigned short* __restrict__ Q,
    const unsigned short* __restrict__ K,
    const unsigned short* __restrict__ V,
    unsigned short* __restrict__ O)
{
    __shared__ __align__(16) unsigned short Ks[64 * 64];  // [key][d], slot XOR-swizzled
    __shared__ __align__(16) unsigned short Vt[64 * 64];  // [d][key], col XOR-swizzled

    const int bh  = blockIdx.x;
    const int b   = bh >> 4;
    const int h   = bh & 15;
    const int pr  = blockIdx.y;
    const int tid = threadIdx.x;
    const int wave = tid >> 6;
    const int lane = tid & 63;
    const int lg   = lane >> 4;    // lane group 0..3
    const int lq   = lane & 15;

    const size_t base = ((size_t)b * SEQ) * D_MODEL + h * DK;
    const unsigned short* Kb = K + base;
    const unsigned short* Vb = V + base;

    const int trow  = tid >> 3;
    const int tslot = tid & 7;
    const int c0s = (tslot ^ (trow & 7)) * 8;
    const int c1s = (tslot ^ ((trow + 32) & 7)) * 8;

    #pragma unroll 1
    for (int half = 0; half < 2; ++half) {
        const int qt  = half ? (NQT - 1 - pr) : pr;
        const int qw  = qt * 64 + wave * 16;
        const int myq = qw + lq;

        bf16x8 qf[2];
        {
            const unsigned short* qp = Q + base + (size_t)myq * D_MODEL + lg * 8;
            qf[0] = __builtin_bit_cast(bf16x8, *reinterpret_cast<const short8*>(qp));
            qf[1] = __builtin_bit_cast(bf16x8, *reinterpret_cast<const short8*>(qp + 32));
        }

        f32x4 acc[4];
        #pragma unroll
        for (int i = 0; i < 4; i++)
            #pragma unroll
            for (int r = 0; r < 4; r++) acc[i][r] = 0.f;
        float m_run = -INFINITY, l_run = 0.f;

        const int nt = qt + 1;
        for (int t = 0; t < nt; ++t) {
            const int m0 = t * 64;
            __syncthreads();   // previous tile's compute done

            gload_lds16(Kb + (size_t)(m0 + trow) * D_MODEL + c0s, Ks + wave * 512);
            gload_lds16(Kb + (size_t)(m0 + trow + 32) * D_MODEL + c1s, Ks + 2048 + wave * 512);
            #pragma unroll
            for (int p = 0; p < 2; ++p) {
                const int d0 = wave * 8 + p * 32;
                union { uint4 v; unsigned short u[8]; } vb;
                vb.v = *reinterpret_cast<const uint4*>(Vb + (size_t)(m0 + lane) * D_MODEL + d0);
                #pragma unroll
                for (int e = 0; e < 8; ++e) {
                    const int d = d0 + e;
                    const int addr = d * 128 + ((lane * 2) ^ ((d & 7) << 4));
                    *reinterpret_cast<unsigned short*>((char*)Vt + addr) = vb.u[e];
                }
            }
            __syncthreads();   // staging visible

            // ---- QK^T (swapped): s[kg] row=key=kg*16+lg*4+r, col=q=lq ----
            f32x4 s[4];
            __builtin_amdgcn_s_setprio(1);
            #pragma unroll
            for (int kg = 0; kg < 4; ++kg) {
                #pragma unroll
                for (int r = 0; r < 4; ++r) s[kg][r] = 0.f;
                #pragma unroll
                for (int ks = 0; ks < 2; ++ks) {
                    const int row  = kg * 16 + lq;
                    const int slot = (ks * 4 + lg) ^ (row & 7);
                    bf16x8 kf = __builtin_bit_cast(bf16x8,
                        *reinterpret_cast<const short8*>((const char*)Ks + row * 128 + slot * 16));
                    s[kg] = __builtin_amdgcn_mfma_f32_16x16x32_bf16(kf, qf[ks], s[kg], 0, 0, 0);
                }
            }
            __builtin_amdgcn_s_setprio(0);

            // ---- scores, mask (diagonal tile only), row max ----
            float sv[4][4];
            #pragma unroll
            for (int kg = 0; kg < 4; ++kg)
                #pragma unroll
                for (int r = 0; r < 4; ++r) sv[kg][r] = s[kg][r] * 0.125f;
            if (t == nt - 1) {
                #pragma unroll
                for (int kg = 0; kg < 4; ++kg)
                    #pragma unroll
                    for (int r = 0; r < 4; ++r)
                        if (m0 + kg * 16 + lg * 4 + r > myq) sv[kg][r] = -INFINITY;
            }
            float mx = sv[0][0];
            #pragma unroll
            for (int kg = 0; kg < 4; ++kg)
                #pragma unroll
                for (int r = 0; r < 4; ++r) mx = fmaxf(mx, sv[kg][r]);
            mx = fmaxf(mx, __shfl_xor(mx, 16));
            mx = fmaxf(mx, __shfl_xor(mx, 32));

            // ---- defer-max (T13): rescale only when max grew by > 8 ----
            if (!__all(mx <= m_run + 8.f)) {
                const float mnew = fmaxf(m_run, mx);
                const float sc   = __expf(m_run - mnew);
                m_run = mnew;
                l_run *= sc;
                float scv[4];
                #pragma unroll
                for (int r = 0; r < 4; ++r) scv[r] = __shfl(sc, lg * 4 + r);
                #pragma unroll
                for (int dg = 0; dg < 4; ++dg)
                    #pragma unroll
                    for (int r = 0; r < 4; ++r) acc[dg][r] *= scv[r];
            }

            float p[4][4];
            float ps = 0.f;
            #pragma unroll
            for (int kg = 0; kg < 4; ++kg)
                #pragma unroll
                for (int r = 0; r < 4; ++r) {
                    p[kg][r] = __expf(sv[kg][r] - m_run);
                    ps += p[kg][r];
                }
            ps += __shfl_xor(ps, 16);
            ps += __shfl_xor(ps, 32);
            l_run += ps;

            // ---- redistribute P into A-frag layout + PV ----
            #pragma unroll
            for (int ks = 0; ks < 2; ++ks) {
                const unsigned int wlo0 = cvtpk_bf16(p[2*ks][0],   p[2*ks][1]);
                const unsigned int wlo1 = cvtpk_bf16(p[2*ks][2],   p[2*ks][3]);
                const unsigned int whi0 = cvtpk_bf16(p[2*ks+1][0], p[2*ks+1][1]);
                const unsigned int whi1 = cvtpk_bf16(p[2*ks+1][2], p[2*ks+1][3]);
                unsigned int aw[4];
                #pragma unroll
                for (int w = 0; w < 4; ++w) {
                    const int src = lq + (((lg & 1) * 2 + (w >> 1)) << 4);
                    const unsigned int t0 = __shfl((w & 1) ? wlo1 : wlo0, src);
                    const unsigned int t1 = __shfl((w & 1) ? whi1 : whi0, src);
                    aw[w] = (lg < 2) ? t0 : t1;
                }
                uint4 awv = make_uint4(aw[0], aw[1], aw[2], aw[3]);
                bf16x8 af = __builtin_bit_cast(bf16x8, awv);
                __builtin_amdgcn_s_setprio(1);
                #pragma unroll
                for (int dg = 0; dg < 4; ++dg) {
                    const int d = dg * 16 + lq;
                    const int addr = d * 128 + ((ks * 64 + lg * 16) ^ ((d & 7) << 4));
                    bf16x8 vf = __builtin_bit_cast(bf16x8,
                        *reinterpret_cast<const short8*>((const char*)Vt + addr));
                    acc[dg] = __builtin_amdgcn_mfma_f32_16x16x32_bf16(af, vf, acc[dg], 0, 0, 0);
                }
                __builtin_amdgcn_s_setprio(0);
            }
        }

        // ---- epilogue ----
        float lv[4];
        #pragma unroll
        for (int r = 0; r < 4; ++r) lv[r] = 1.0f / __shfl(l_run, lg * 4 + r);
        #pragma unroll
        for (int dg = 0; dg < 4; ++dg)
            #pragma unroll
            for (int r = 0; r < 4; ++r) {
                const int qrow = qw + lg * 4 + r;
                O[base + (size_t)qrow * D_MODEL + dg * 16 + lq] = f2bf(acc[dg][r] * lv[r]);
            }
    }
}

// ---------------- launch ----------------
extern "C" void kernel_launch(void* const* d_in, const int* in_sizes, int n_in,
                              void* d_out, int out_size, void* d_ws, size_t ws_size,
                              hipStream_t stream) {
    const float* x  = (const float*)d_in[0];
    const float* wq = (const float*)d_in[1];
    const float* wk = (const float*)d_in[2];
    const float* wv = (const float*)d_in[3];
    const float* wo = (const float*)d_in[4];

    char* ws = (char*)d_ws;
    const size_t NXB = (size_t)MROWS * D_MODEL * 2;   // 16 MiB bf16 x
    const size_t NWB = (size_t)D_MODEL * D_MODEL * 2; // 2 MiB bf16 weight

    unsigned short* xb  = (unsigned short*)(ws);
    unsigned short* wqb = (unsigned short*)(ws + NXB);
    unsigned short* wkb = (unsigned short*)(ws + NXB + NWB);
    unsigned short* wvb = (unsigned short*)(ws + NXB + 2 * NWB);
    unsigned short* wob = (unsigned short*)(ws + NXB + 3 * NWB);
    unsigned short* Qb  = (unsigned short*)(ws + NXB + 4 * NWB);
    unsigned short* Kb  = (unsigned short*)(ws + NXB + 4 * NWB + NXB);
    unsigned short* Vb  = (unsigned short*)(ws + NXB + 4 * NWB + 2 * NXB);
    unsigned short* Ab  = (unsigned short*)(ws + NXB + 4 * NWB + 3 * NXB);

    const int NX = MROWS * D_MODEL;
    const int NW = D_MODEL * D_MODEL;

    cvt_bf16<<<NX / 1024, 256, 0, stream>>>(x, xb, NX);
    dim3 gw(NW / 1024, 4, 1);
    cvt_bf16_w<<<gw, 256, 0, stream>>>(wq, wk, wv, wo, wqb, wkb, wvb, wob, NW);

    dim3 gqkv(MROWS / BM, D_MODEL / BN, 3);
    gemm_bt<<<gqkv, 256, 0, stream>>>(xb, wqb, wkb, wvb, Qb, Kb, Vb,
                                      MROWS, D_MODEL, D_MODEL, 0);

    dim3 gattn(BATCH * NHEADS, NQT / 2, 1);
    attn_mfma<<<gattn, 256, 0, stream>>>(Qb, Kb, Vb, Ab);

    dim3 gout(MROWS / BM, D_MODEL / BN, 1);
    gemm_bt<<<gout, 256, 0, stream>>>(Ab, wob, wob, wob, d_out, d_out, d_out,
                                      MROWS, D_MODEL, D_MODEL, 1);
}

// Round 6
// 200.265 us; speedup vs baseline: 1.1217x; 1.1217x over previous
//
#include <hip/hip_runtime.h>
#include <hip/hip_bf16.h>
#include <cstdint>

#define D_MODEL 1024
#define NHEADS  16
#define DK      64
#define BATCH   4
#define SEQ     2048
#define MROWS   (BATCH * SEQ)   // 8192
#define NQT     (SEQ / 64)      // 32 q-tiles

typedef __attribute__((ext_vector_type(4))) float  f32x4;
typedef __attribute__((ext_vector_type(8))) __bf16 bf16x8;
typedef __attribute__((ext_vector_type(8))) short  short8;

__device__ __forceinline__ unsigned short f2bf(float f) {
    unsigned int u = __float_as_uint(f);
    unsigned int r = (u + 0x7fffu + ((u >> 16) & 1u)) >> 16;
    return (unsigned short)r;
}

__device__ __forceinline__ unsigned int cvtpk_bf16(float lo, float hi) {
    unsigned int r;
    asm volatile("v_cvt_pk_bf16_f32 %0, %1, %2" : "=v"(r) : "v"(lo), "v"(hi));
    return r;
}

// ---------------- fp32 -> bf16 conversion ----------------
__global__ void cvt_bf16(const float* __restrict__ in, unsigned short* __restrict__ out, int n) {
    int i = (blockIdx.x * 256 + threadIdx.x) * 4;
    if (i >= n) return;
    float4 v = *reinterpret_cast<const float4*>(in + i);
    ushort4 o;
    o.x = f2bf(v.x); o.y = f2bf(v.y); o.z = f2bf(v.z); o.w = f2bf(v.w);
    *reinterpret_cast<ushort4*>(out + i) = o;
}

__global__ void cvt_bf16_w(const float* __restrict__ w0, const float* __restrict__ w1,
                           const float* __restrict__ w2, const float* __restrict__ w3,
                           unsigned short* __restrict__ o0, unsigned short* __restrict__ o1,
                           unsigned short* __restrict__ o2, unsigned short* __restrict__ o3,
                           int n) {
    const int z = blockIdx.y;
    const float* in = (z == 0) ? w0 : (z == 1) ? w1 : (z == 2) ? w2 : w3;
    unsigned short* out = (z == 0) ? o0 : (z == 1) ? o1 : (z == 2) ? o2 : o3;
    int i = (blockIdx.x * 256 + threadIdx.x) * 4;
    if (i >= n) return;
    float4 v = *reinterpret_cast<const float4*>(in + i);
    ushort4 o;
    o.x = f2bf(v.x); o.y = f2bf(v.y); o.z = f2bf(v.z); o.w = f2bf(v.w);
    *reinterpret_cast<ushort4*>(out + i) = o;
}

// ---------------- async global->LDS (16B per lane) ----------------
__device__ __forceinline__ void gload_lds16(const void* g, void* l) {
    __builtin_amdgcn_global_load_lds(
        (const __attribute__((address_space(1))) void*)(uintptr_t)g,
        (__attribute__((address_space(3))) void*)(unsigned int)(uintptr_t)l,
        16, 0, 0);
}

// ---------------- bf16 MFMA GEMM, 2-phase double-buffered pipeline ----------------
// C[M][N] = A[M][K] * Bt[N][K]^T
#define BM 128
#define BN 128
#define BK 32

__global__ __launch_bounds__(256) void gemm_bt(
    const unsigned short* __restrict__ A,
    const unsigned short* __restrict__ B0,
    const unsigned short* __restrict__ B1,
    const unsigned short* __restrict__ B2,
    void* __restrict__ C0, void* __restrict__ C1, void* __restrict__ C2,
    int M, int N, int K, int out_f32)
{
    __shared__ __align__(16) unsigned short As[2][BM * BK];
    __shared__ __align__(16) unsigned short Bs[2][BN * BK];

    const int z = blockIdx.z;
    const unsigned short* Bt = (z == 0) ? B0 : ((z == 1) ? B1 : B2);
    void* C = (z == 0) ? C0 : ((z == 1) ? C1 : C2);

    const int tid  = threadIdx.x;
    const int wave = tid >> 6;
    const int lane = tid & 63;
    const int wr   = wave >> 1;   // 0..1
    const int wc   = wave & 1;    // 0..1
    const int bm   = blockIdx.x * BM;
    const int bn   = blockIdx.y * BN;

    f32x4 acc[4][4];
    #pragma unroll
    for (int i = 0; i < 4; i++)
        #pragma unroll
        for (int j = 0; j < 4; j++)
            #pragma unroll
            for (int r = 0; r < 4; r++) acc[i][j][r] = 0.f;

    const int srow = tid >> 2;          // 0..63
    const int scol = (tid & 3) * 8;     // 0,8,16,24

    const int kg = (lane >> 4) * 8;
    const int rl = lane & 15;

    const unsigned short* Arow0 = A  + (size_t)(bm + srow) * K + scol;
    const unsigned short* Arow1 = A  + (size_t)(bm + 64 + srow) * K + scol;
    const unsigned short* Brow0 = Bt + (size_t)(bn + srow) * K + scol;
    const unsigned short* Brow1 = Bt + (size_t)(bn + 64 + srow) * K + scol;

    auto STAGE = [&](int buf, int k0) {
        gload_lds16(Arow0 + k0, &As[buf][0] + wave * 512);
        gload_lds16(Arow1 + k0, &As[buf][0] + 2048 + wave * 512);
        gload_lds16(Brow0 + k0, &Bs[buf][0] + wave * 512);
        gload_lds16(Brow1 + k0, &Bs[buf][0] + 2048 + wave * 512);
    };

    auto COMPUTE = [&](int buf) {
        bf16x8 a[4], b[4];
        #pragma unroll
        for (int mi = 0; mi < 4; mi++) {
            short8 t = *reinterpret_cast<const short8*>(&As[buf][(wr * 64 + mi * 16 + rl) * BK + kg]);
            a[mi] = __builtin_bit_cast(bf16x8, t);
        }
        #pragma unroll
        for (int ni = 0; ni < 4; ni++) {
            short8 t = *reinterpret_cast<const short8*>(&Bs[buf][(wc * 64 + ni * 16 + rl) * BK + kg]);
            b[ni] = __builtin_bit_cast(bf16x8, t);
        }
        #pragma unroll
        for (int mi = 0; mi < 4; mi++)
            #pragma unroll
            for (int ni = 0; ni < 4; ni++)
                acc[mi][ni] = __builtin_amdgcn_mfma_f32_16x16x32_bf16(a[mi], b[ni], acc[mi][ni], 0, 0, 0);
    };

    const int NT = K / BK;

    STAGE(0, 0);
    __syncthreads();

    int cur = 0;
    for (int t = 0; t < NT - 1; ++t) {
        STAGE(cur ^ 1, (t + 1) * BK);
        COMPUTE(cur);
        __syncthreads();
        cur ^= 1;
    }
    COMPUTE(cur);

    const int rg = (lane >> 4) * 4;
    if (out_f32) {
        #pragma unroll
        for (int mi = 0; mi < 4; mi++)
            #pragma unroll
            for (int ni = 0; ni < 4; ni++)
                #pragma unroll
                for (int r = 0; r < 4; r++) {
                    int row = bm + wr * 64 + mi * 16 + rg + r;
                    int col = bn + wc * 64 + ni * 16 + rl;
                    ((float*)C)[(size_t)row * N + col] = acc[mi][ni][r];
                }
    } else {
        #pragma unroll
        for (int mi = 0; mi < 4; mi++)
            #pragma unroll
            for (int ni = 0; ni < 4; ni++)
                #pragma unroll
                for (int r = 0; r < 4; r++) {
                    int row = bm + wr * 64 + mi * 16 + rg + r;
                    int col = bn + wc * 64 + ni * 16 + rl;
                    ((unsigned short*)C)[(size_t)row * N + col] = f2bf(acc[mi][ni][r]);
                }
    }
}

// ---------------- MFMA causal flash attention, double-buffered KV ----------------
// grid: (B*H, NQT); qt = NQT-1-blockIdx.y (longest blocks dispatched first).
__global__ __launch_bounds__(256) void attn_mfma(
    const unsigned short* __restrict__ Q,
    const unsigned short* __restrict__ K,
    const unsigned short* __restrict__ V,
    unsigned short* __restrict__ O)
{
    __shared__ __align__(16) unsigned short Ks[2][64 * 64];  // [key][d], slot XOR-swizzled
    __shared__ __align__(16) unsigned short Vt[2][64 * 64];  // [d][key], col XOR-swizzled

    const int bh  = blockIdx.x;
    const int b   = bh >> 4;
    const int h   = bh & 15;
    const int qt  = NQT - 1 - blockIdx.y;   // LPT: longest first
    const int tid = threadIdx.x;
    const int wave = tid >> 6;
    const int lane = tid & 63;
    const int lg   = lane >> 4;    // lane group 0..3
    const int lq   = lane & 15;

    const size_t base = ((size_t)b * SEQ) * D_MODEL + h * DK;
    const unsigned short* Kb = K + base;
    const unsigned short* Vb = V + base;

    const int qw  = qt * 64 + wave * 16;
    const int myq = qw + lq;

    bf16x8 qf[2];
    {
        const unsigned short* qp = Q + base + (size_t)myq * D_MODEL + lg * 8;
        qf[0] = __builtin_bit_cast(bf16x8, *reinterpret_cast<const short8*>(qp));
        qf[1] = __builtin_bit_cast(bf16x8, *reinterpret_cast<const short8*>(qp + 32));
    }

    f32x4 acc[4];
    #pragma unroll
    for (int i = 0; i < 4; i++)
        #pragma unroll
        for (int r = 0; r < 4; r++) acc[i][r] = 0.f;
    float m_run = -INFINITY, l_run = 0.f;

    const int trow  = tid >> 3;
    const int tslot = tid & 7;
    const int c0s = (tslot ^ (trow & 7)) * 8;   // pre-swizzled K source col (rows 0-31)
    const int c1s = c0s;                        // (trow+32)&7 == trow&7

    union { uint4 v; unsigned short u[8]; } vpre[2];

    const int nt = qt + 1;

    // ---- prologue: stage tile 0 into buffer 0 ----
    gload_lds16(Kb + (size_t)trow * D_MODEL + c0s,        &Ks[0][0] + wave * 512);
    gload_lds16(Kb + (size_t)(trow + 32) * D_MODEL + c1s, &Ks[0][0] + 2048 + wave * 512);
    vpre[0].v = *reinterpret_cast<const uint4*>(Vb + (size_t)lane * D_MODEL + wave * 8);
    vpre[1].v = *reinterpret_cast<const uint4*>(Vb + (size_t)lane * D_MODEL + wave * 8 + 32);
    #pragma unroll
    for (int p = 0; p < 2; ++p) {
        const int d0 = wave * 8 + p * 32;
        #pragma unroll
        for (int e = 0; e < 8; ++e) {
            const int d = d0 + e;
            const int addr = d * 128 + ((lane * 2) ^ ((d & 7) << 4));
            *reinterpret_cast<unsigned short*>((char*)&Vt[0][0] + addr) = vpre[p].u[e];
        }
    }
    __syncthreads();

    for (int t = 0; t < nt; ++t) {
        const int c = t & 1;
        const bool pf = (t + 1 < nt);

        // ---- prefetch tile t+1 (K async->LDS, V ->regs) ----
        if (pf) {
            const int m1 = (t + 1) * 64;
            gload_lds16(Kb + (size_t)(m1 + trow) * D_MODEL + c0s,      &Ks[c ^ 1][0] + wave * 512);
            gload_lds16(Kb + (size_t)(m1 + trow + 32) * D_MODEL + c1s, &Ks[c ^ 1][0] + 2048 + wave * 512);
            vpre[0].v = *reinterpret_cast<const uint4*>(Vb + (size_t)(m1 + lane) * D_MODEL + wave * 8);
            vpre[1].v = *reinterpret_cast<const uint4*>(Vb + (size_t)(m1 + lane) * D_MODEL + wave * 8 + 32);
        }

        const int m0 = t * 64;

        // ---- QK^T (swapped): s[kg] row=key=kg*16+lg*4+r, col=q=lq ----
        f32x4 s[4];
        __builtin_amdgcn_s_setprio(1);
        #pragma unroll
        for (int kg = 0; kg < 4; ++kg) {
            #pragma unroll
            for (int r = 0; r < 4; ++r) s[kg][r] = 0.f;
            #pragma unroll
            for (int ks = 0; ks < 2; ++ks) {
                const int row  = kg * 16 + lq;
                const int slot = (ks * 4 + lg) ^ (row & 7);
                bf16x8 kf = __builtin_bit_cast(bf16x8,
                    *reinterpret_cast<const short8*>((const char*)&Ks[c][0] + row * 128 + slot * 16));
                s[kg] = __builtin_amdgcn_mfma_f32_16x16x32_bf16(kf, qf[ks], s[kg], 0, 0, 0);
            }
        }
        __builtin_amdgcn_s_setprio(0);

        // ---- scores, mask (diagonal tile only), row max ----
        float sv[4][4];
        #pragma unroll
        for (int kg = 0; kg < 4; ++kg)
            #pragma unroll
            for (int r = 0; r < 4; ++r) sv[kg][r] = s[kg][r] * 0.125f;
        if (t == nt - 1) {
            #pragma unroll
            for (int kg = 0; kg < 4; ++kg)
                #pragma unroll
                for (int r = 0; r < 4; ++r)
                    if (m0 + kg * 16 + lg * 4 + r > myq) sv[kg][r] = -INFINITY;
        }
        float mx = sv[0][0];
        #pragma unroll
        for (int kg = 0; kg < 4; ++kg)
            #pragma unroll
            for (int r = 0; r < 4; ++r) mx = fmaxf(mx, sv[kg][r]);
        mx = fmaxf(mx, __shfl_xor(mx, 16));
        mx = fmaxf(mx, __shfl_xor(mx, 32));

        // ---- defer-max (T13): rescale only when max grew by > 8 ----
        if (!__all(mx <= m_run + 8.f)) {
            const float mnew = fmaxf(m_run, mx);
            const float sc   = __expf(m_run - mnew);
            m_run = mnew;
            l_run *= sc;
            float scv[4];
            #pragma unroll
            for (int r = 0; r < 4; ++r) scv[r] = __shfl(sc, lg * 4 + r);
            #pragma unroll
            for (int dg = 0; dg < 4; ++dg)
                #pragma unroll
                for (int r = 0; r < 4; ++r) acc[dg][r] *= scv[r];
        }

        float p[4][4];
        float ps = 0.f;
        #pragma unroll
        for (int kg = 0; kg < 4; ++kg)
            #pragma unroll
            for (int r = 0; r < 4; ++r) {
                p[kg][r] = __expf(sv[kg][r] - m_run);
                ps += p[kg][r];
            }
        ps += __shfl_xor(ps, 16);
        ps += __shfl_xor(ps, 32);
        l_run += ps;

        // ---- redistribute P into A-frag layout + PV ----
        #pragma unroll
        for (int ks = 0; ks < 2; ++ks) {
            const unsigned int wlo0 = cvtpk_bf16(p[2*ks][0],   p[2*ks][1]);
            const unsigned int wlo1 = cvtpk_bf16(p[2*ks][2],   p[2*ks][3]);
            const unsigned int whi0 = cvtpk_bf16(p[2*ks+1][0], p[2*ks+1][1]);
            const unsigned int whi1 = cvtpk_bf16(p[2*ks+1][2], p[2*ks+1][3]);
            unsigned int aw[4];
            #pragma unroll
            for (int w = 0; w < 4; ++w) {
                const int src = lq + (((lg & 1) * 2 + (w >> 1)) << 4);
                const unsigned int t0 = __shfl((w & 1) ? wlo1 : wlo0, src);
                const unsigned int t1 = __shfl((w & 1) ? whi1 : whi0, src);
                aw[w] = (lg < 2) ? t0 : t1;
            }
            uint4 awv = make_uint4(aw[0], aw[1], aw[2], aw[3]);
            bf16x8 af = __builtin_bit_cast(bf16x8, awv);
            __builtin_amdgcn_s_setprio(1);
            #pragma unroll
            for (int dg = 0; dg < 4; ++dg) {
                const int d = dg * 16 + lq;
                const int addr = d * 128 + ((ks * 64 + lg * 16) ^ ((d & 7) << 4));
                bf16x8 vf = __builtin_bit_cast(bf16x8,
                    *reinterpret_cast<const short8*>((const char*)&Vt[c][0] + addr));
                acc[dg] = __builtin_amdgcn_mfma_f32_16x16x32_bf16(af, vf, acc[dg], 0, 0, 0);
            }
            __builtin_amdgcn_s_setprio(0);
        }

        // ---- write prefetched V into next buffer (after PV reads of Vt[c]) ----
        if (pf) {
            #pragma unroll
            for (int p2 = 0; p2 < 2; ++p2) {
                const int d0 = wave * 8 + p2 * 32;
                #pragma unroll
                for (int e = 0; e < 8; ++e) {
                    const int d = d0 + e;
                    const int addr = d * 128 + ((lane * 2) ^ ((d & 7) << 4));
                    *reinterpret_cast<unsigned short*>((char*)&Vt[c ^ 1][0] + addr) = vpre[p2].u[e];
                }
            }
        }
        __syncthreads();
    }

    // ---- epilogue ----
    float lv[4];
    #pragma unroll
    for (int r = 0; r < 4; ++r) lv[r] = 1.0f / __shfl(l_run, lg * 4 + r);
    #pragma unroll
    for (int dg = 0; dg < 4; ++dg)
        #pragma unroll
        for (int r = 0; r < 4; ++r) {
            const int qrow = qw + lg * 4 + r;
            O[base + (size_t)qrow * D_MODEL + dg * 16 + lq] = f2bf(acc[dg][r] * lv[r]);
        }
}

// ---------------- launch ----------------
extern "C" void kernel_launch(void* const* d_in, const int* in_sizes, int n_in,
                              void* d_out, int out_size, void* d_ws, size_t ws_size,
                              hipStream_t stream) {
    const float* x  = (const float*)d_in[0];
    const float* wq = (const float*)d_in[1];
    const float* wk = (const float*)d_in[2];
    const float* wv = (const float*)d_in[3];
    const float* wo = (const float*)d_in[4];

    char* ws = (char*)d_ws;
    const size_t NXB = (size_t)MROWS * D_MODEL * 2;   // 16 MiB bf16 x
    const size_t NWB = (size_t)D_MODEL * D_MODEL * 2; // 2 MiB bf16 weight

    unsigned short* xb  = (unsigned short*)(ws);
    unsigned short* wqb = (unsigned short*)(ws + NXB);
    unsigned short* wkb = (unsigned short*)(ws + NXB + NWB);
    unsigned short* wvb = (unsigned short*)(ws + NXB + 2 * NWB);
    unsigned short* wob = (unsigned short*)(ws + NXB + 3 * NWB);
    unsigned short* Qb  = (unsigned short*)(ws + NXB + 4 * NWB);
    unsigned short* Kb  = (unsigned short*)(ws + NXB + 4 * NWB + NXB);
    unsigned short* Vb  = (unsigned short*)(ws + NXB + 4 * NWB + 2 * NXB);
    unsigned short* Ab  = (unsigned short*)(ws + NXB + 4 * NWB + 3 * NXB);

    const int NX = MROWS * D_MODEL;
    const int NW = D_MODEL * D_MODEL;

    cvt_bf16<<<NX / 1024, 256, 0, stream>>>(x, xb, NX);
    dim3 gw(NW / 1024, 4, 1);
    cvt_bf16_w<<<gw, 256, 0, stream>>>(wq, wk, wv, wo, wqb, wkb, wvb, wob, NW);

    dim3 gqkv(MROWS / BM, D_MODEL / BN, 3);
    gemm_bt<<<gqkv, 256, 0, stream>>>(xb, wqb, wkb, wvb, Qb, Kb, Vb,
                                      MROWS, D_MODEL, D_MODEL, 0);

    dim3 gattn(BATCH * NHEADS, NQT, 1);
    attn_mfma<<<gattn, 256, 0, stream>>>(Qb, Kb, Vb, Ab);

    dim3 gout(MROWS / BM, D_MODEL / BN, 1);
    gemm_bt<<<gout, 256, 0, stream>>>(Ab, wob, wob, wob, d_out, d_out, d_out,
                                      MROWS, D_MODEL, D_MODEL, 1);
}